// Round 1
// 483.063 us; speedup vs baseline: 1.1109x; 1.1109x over previous
//
#include <hip/hip_runtime.h>
#include <hip/hip_bf16.h>

#define Sdim 4096
#define Ndim 32
#define Hdim 512
#define Mdim (Sdim * Ndim)

#define BM 128
#define BN 256
#define BK 64

typedef __bf16 bf16x8 __attribute__((ext_vector_type(8)));
typedef float f32x4 __attribute__((ext_vector_type(4)));
typedef unsigned short ushort8v __attribute__((ext_vector_type(8)));

__device__ __forceinline__ void load_lds16(const void* g, void* l) {
    __builtin_amdgcn_global_load_lds(
        (const __attribute__((address_space(1))) void*)g,
        (__attribute__((address_space(3))) void*)l, 16, 0, 0);
}

__device__ __forceinline__ float ftanh(float x) {
    float e = __expf(2.f * x);
    return 1.f - 2.f / (e + 1.f);
}

// ---------------- bias[n][c] = hidden[n]·Ww[c] + Wb[c] + Ub[c]
__global__ __launch_bounds__(256) void k_prep_bias(
    const float* __restrict__ hidden, const float* __restrict__ Ww,
    const float* __restrict__ Wb, const float* __restrict__ Ubias,
    float* __restrict__ bias) {
    const int t = threadIdx.x, w = t >> 6, lane = t & 63;
    const int cc = blockIdx.x * 4 + w;
    const float4 w0 = *(const float4*)(Ww + (size_t)cc * Hdim + lane * 8);
    const float4 w1 = *(const float4*)(Ww + (size_t)cc * Hdim + lane * 8 + 4);
    const float wb = Wb[cc] + Ubias[cc];
    for (int n = 0; n < Ndim; ++n) {
        const float4 h0 = *(const float4*)(hidden + n * Hdim + lane * 8);
        const float4 h1 = *(const float4*)(hidden + n * Hdim + lane * 8 + 4);
        float p = w0.x * h0.x + w0.y * h0.y + w0.z * h0.z + w0.w * h0.w +
                  w1.x * h1.x + w1.y * h1.y + w1.z * h1.z + w1.w * h1.w;
        p += __shfl_xor(p, 1);  p += __shfl_xor(p, 2);
        p += __shfl_xor(p, 4);  p += __shfl_xor(p, 8);
        p += __shfl_xor(p, 16); p += __shfl_xor(p, 32);
        if (lane == 0) bias[n * Hdim + cc] = p + wb;
    }
}

// ---------------- U_w fp32 -> bf16 (packed cvt)
__global__ __launch_bounds__(256) void k_cvt(
    const float* __restrict__ src, unsigned short* __restrict__ dst) {
    const int i = blockIdx.x * 256 + threadIdx.x;
    float4 v = ((const float4*)src)[i];
    union { __hip_bfloat162 h[2]; ushort4 u; } r;
    r.h[0] = __float22bfloat162_rn(make_float2(v.x, v.y));
    r.h[1] = __float22bfloat162_rn(make_float2(v.z, v.w));
    ((ushort4*)dst)[i] = r.u;
}

// ---------------- fused partial score, BK=64, prefetch-pipelined
// Per K-step: raw barrier (no drain) -> issue B global_load_lds (4) ->
// cvt+write A (from regs prefetched last step) -> issue next A loads (4) ->
// s_waitcnt vmcnt(4) (A prefetch stays in flight!) -> raw barrier -> MFMA.
__global__ __launch_bounds__(512, 4) void k_gemm_score(
    const float* __restrict__ enc,          // [M, H] fp32
    const unsigned short* __restrict__ Ub,  // [H, H] bf16, row=out col
    const float* __restrict__ bias,         // [N, H]
    const float* __restrict__ vw,           // [H]
    float* __restrict__ scorep) {           // [2][N, S] partials
    __shared__ __align__(16) unsigned short Asm[BM][72];  // 144B rows (pad)
    __shared__ __align__(16) unsigned short Bsm[BN * BK]; // linear, swizzled
    __shared__ float ssm[4][BM];

    const int t = threadIdx.x;
    const int lane = t & 63;
    const int w = t >> 6;
    const int wM = w >> 2;
    const int wN = w & 3;
    const int c = lane & 15;
    const int q = lane >> 4;

    const int rowblk = blockIdx.x >> 1;
    const int colblk = blockIdx.x & 1;
    const int mBase = rowblk * BM;
    const int colBase = colblk * BN;

    // A staging: thread -> row t>>2, 16-float chunk t&3 (64B load)
    const int ar = t >> 2;
    const int aq = t & 3;
    const int asw = ((ar >> 3) & 1) << 1;  // XOR on 16B-chunk bit1
    const float4* arow =
        (const float4*)(enc + (size_t)(mBase + ar) * Hdim) + aq * 4;
    unsigned short* awr = &Asm[ar][((2 * aq) ^ asw) * 8];

    // B staging: 4 global_load_lds/thread; source chunk XOR-swizzled by col&7
    const int coff = lane >> 3;            // col within 8-col group
    const int bch = (lane & 7) ^ coff;     // pre-swizzled source chunk
    const unsigned short* bsrc =
        Ub + (size_t)(colBase + w * 8 + coff) * Hdim + bch * 8;
    unsigned short* bdst = Bsm + (w * 8) * BK;

    const int sA = ((c >> 3) & 1) << 1;  // A un-swizzle (lane const)
    const int sB = c & 7;                // B un-swizzle (lane const)

    f32x4 acc[4][4];
#pragma unroll
    for (int i = 0; i < 4; ++i)
#pragma unroll
        for (int j = 0; j < 4; ++j) acc[i][j] = (f32x4){0.f, 0.f, 0.f, 0.f};

    // prologue: issue A(0)
    float4 a0 = arow[0], a1 = arow[1], a2 = arow[2], a3 = arow[3];

#pragma unroll 1
    for (int kk = 0; kk < Hdim / BK; ++kk) {
        // barrier #1: all waves done reading LDS of step kk-1.
        // Raw s_barrier: does NOT drain the in-flight A prefetch.
        asm volatile("" ::: "memory");
        __builtin_amdgcn_s_barrier();
        asm volatile("" ::: "memory");
        __builtin_amdgcn_sched_barrier(0);

        // issue B(kk): 4 x 1KB direct-to-LDS (oldest vmem ops this step)
#pragma unroll
        for (int g = 0; g < 4; ++g)
            load_lds16(bsrc + (size_t)g * 64 * Hdim + kk * BK,
                       bdst + g * 64 * BK);
        asm volatile("" ::: "memory");
        __builtin_amdgcn_sched_barrier(0);

        // cvt A(kk) regs -> LDS (compiler waits only the 4 A loads)
        union { __hip_bfloat162 h[4]; ushort8v v; } p0, p1;
        p0.h[0] = __float22bfloat162_rn(make_float2(a0.x, a0.y));
        p0.h[1] = __float22bfloat162_rn(make_float2(a0.z, a0.w));
        p0.h[2] = __float22bfloat162_rn(make_float2(a1.x, a1.y));
        p0.h[3] = __float22bfloat162_rn(make_float2(a1.z, a1.w));
        p1.h[0] = __float22bfloat162_rn(make_float2(a2.x, a2.y));
        p1.h[1] = __float22bfloat162_rn(make_float2(a2.z, a2.w));
        p1.h[2] = __float22bfloat162_rn(make_float2(a3.x, a3.y));
        p1.h[3] = __float22bfloat162_rn(make_float2(a3.z, a3.w));
        *(ushort8v*)awr = p0.v;
        *(ushort8v*)(awr + 8) = p1.v;

        // issue A(kk+1) prefetch (4 newest vmem ops; clamped tail reload
        // keeps the vmcnt count exact — kept live after the loop)
        const int kn = (kk < Hdim / BK - 1) ? kk + 1 : kk;
        const float4* ap = arow + kn * 16;
        a0 = ap[0]; a1 = ap[1]; a2 = ap[2]; a3 = ap[3];

        asm volatile("" ::: "memory");
        __builtin_amdgcn_sched_barrier(0);
        // wait B done + A-writes visible; A prefetch (4) stays in flight
        asm volatile("s_waitcnt vmcnt(4) lgkmcnt(0)" ::: "memory");
        __builtin_amdgcn_s_barrier();
        asm volatile("" ::: "memory");
        __builtin_amdgcn_sched_barrier(0);

        // compute: 2 k-halves of 16 MFMA (no h-unroll: VGPR <= 128 cap)
#pragma unroll 1
        for (int h = 0; h < 2; ++h) {
            bf16x8 af[4], bfr[4];
#pragma unroll
            for (int mi = 0; mi < 4; ++mi) {
                const int row = wM * 64 + mi * 16 + c;
                af[mi] =
                    *(const bf16x8*)&Asm[row][(((h << 2) | q) ^ sA) * 8];
            }
#pragma unroll
            for (int ni = 0; ni < 4; ++ni) {
                const int lc = wN * 64 + ni * 16 + c;
                bfr[ni] = *(const bf16x8*)&Bsm[lc * BK +
                                               (((h << 2) | q) ^ sB) * 8];
            }
#pragma unroll
            for (int mi = 0; mi < 4; ++mi)
#pragma unroll
                for (int ni = 0; ni < 4; ++ni)
                    acc[mi][ni] = __builtin_amdgcn_mfma_f32_16x16x32_bf16(
                        af[mi], bfr[ni], acc[mi][ni], 0, 0, 0);
        }
    }
    // keep tail prefetch live (rule #17): DCE would break the vmcnt(4) count
    asm volatile("" :: "v"(a0.x), "v"(a1.x), "v"(a2.x), "v"(a3.x));

    // epilogue: per-row partial of v·tanh(acc + bias)  (v_b cancels)
    float vcol[4];
#pragma unroll
    for (int ni = 0; ni < 4; ++ni)
        vcol[ni] = vw[colBase + wN * 64 + ni * 16 + c];

#pragma unroll
    for (int mi = 0; mi < 4; ++mi) {
#pragma unroll
        for (int reg = 0; reg < 4; ++reg) {
            const int rl = wM * 64 + mi * 16 + q * 4 + reg;
            const int n = rl & 31;  // mBase % 32 == 0
            float p = 0.f;
#pragma unroll
            for (int ni = 0; ni < 4; ++ni) {
                const int col = colBase + wN * 64 + ni * 16 + c;
                float e = acc[mi][ni][reg] + bias[n * Hdim + col];
                p += vcol[ni] * ftanh(e);
            }
            p += __shfl_xor(p, 1);
            p += __shfl_xor(p, 2);
            p += __shfl_xor(p, 4);
            p += __shfl_xor(p, 8);
            if (c == 0) ssm[wN][rl] = p;
        }
    }
    __syncthreads();
    if (t < BM) {
        const int m = mBase + t;
        const float s = ssm[0][t] + ssm[1][t] + ssm[2][t] + ssm[3][t];
        scorep[colblk * Mdim + (m & 31) * Sdim + (m >> 5)] = s;
    }
}

// ---------------- softmax over S per n; score = score0 + score1
__global__ __launch_bounds__(256) void k_softmax(
    const float* __restrict__ scorep,  // [2][N][S]
    float* __restrict__ out_w) {       // d_out+16384, [S][N]
    const int n = blockIdx.x;
    const int t = threadIdx.x;
    const int w = t >> 6;
    __shared__ float row[Sdim];
    __shared__ float red[8];
    const float4* s0 = (const float4*)(scorep + n * Sdim);
    const float4* s1 = (const float4*)(scorep + Mdim + n * Sdim);

    float mx = -1e30f;
    for (int i = t; i < Sdim / 4; i += 256) {
        float4 a = s0[i], b = s1[i];
        float4 v;
        v.x = a.x + b.x; v.y = a.y + b.y; v.z = a.z + b.z; v.w = a.w + b.w;
        ((float4*)row)[i] = v;
        mx = fmaxf(mx, fmaxf(fmaxf(v.x, v.y), fmaxf(v.z, v.w)));
    }
#pragma unroll
    for (int o = 32; o > 0; o >>= 1) mx = fmaxf(mx, __shfl_xor(mx, o));
    if ((t & 63) == 0) red[w] = mx;
    __syncthreads();
    mx = fmaxf(fmaxf(red[0], red[1]), fmaxf(red[2], red[3]));

    float sum = 0.f;
    for (int i = t; i < Sdim; i += 256) sum += __expf(row[i] - mx);
#pragma unroll
    for (int o = 32; o > 0; o >>= 1) sum += __shfl_xor(sum, o);
    if ((t & 63) == 0) red[4 + w] = sum;
    __syncthreads();
    sum = red[4] + red[5] + red[6] + red[7];
    const float inv = 1.f / sum;
    for (int i = t; i < Sdim; i += 256)
        out_w[i * Ndim + n] = __expf(row[i] - mx) * inv;
}

// ---------------- context partials: part[sc][n][h] = sum_{s in chunk} w*enc
// 512 threads: 8 rows in flight per block (2x the waves of the old version)
__global__ __launch_bounds__(512) void k_context(
    const float* __restrict__ enc, const float* __restrict__ wts,  // [S][N]
    float* __restrict__ part) {
    const int n = blockIdx.x & 31;
    const int sc = blockIdx.x >> 5;  // 0..15
    const int s0 = sc * 256;
    const int t = threadIdx.x;
    const int g = t >> 6;    // 0..7: row slice
    const int lane = t & 63;
    const int h0 = lane * 8;
    float4 c0 = {0.f, 0.f, 0.f, 0.f}, c1 = {0.f, 0.f, 0.f, 0.f};
#pragma unroll 4
    for (int it = 0; it < 32; ++it) {
        const int s = s0 + it * 8 + g;
        const float wv = wts[(size_t)s * Ndim + n];
        const float* e = enc + ((size_t)s * Ndim + n) * Hdim + h0;
        const float4 e0 = *(const float4*)e;
        const float4 e1 = *(const float4*)(e + 4);
        c0.x += wv * e0.x; c0.y += wv * e0.y;
        c0.z += wv * e0.z; c0.w += wv * e0.w;
        c1.x += wv * e1.x; c1.y += wv * e1.y;
        c1.z += wv * e1.z; c1.w += wv * e1.w;
    }
    __shared__ __align__(16) float4 red[7][128];
    if (g > 0) { red[g - 1][lane * 2] = c0; red[g - 1][lane * 2 + 1] = c1; }
    __syncthreads();
    if (g == 0) {
#pragma unroll
        for (int i = 0; i < 7; ++i) {
            const float4 b0 = red[i][lane * 2];
            const float4 b1 = red[i][lane * 2 + 1];
            c0.x += b0.x; c0.y += b0.y; c0.z += b0.z; c0.w += b0.w;
            c1.x += b1.x; c1.y += b1.y; c1.z += b1.z; c1.w += b1.w;
        }
        float* o = part + (size_t)(sc * 32 + n) * Hdim + h0;
        *(float4*)o = c0;
        *(float4*)(o + 4) = c1;
    }
}

// ---------------- reduce 16 partial chunks -> context [N,H]
__global__ __launch_bounds__(256) void k_ctx_reduce(
    const float* __restrict__ part, float* __restrict__ out) {
    const int j = blockIdx.x * 256 + threadIdx.x;  // float4 index, 4096 total
    float4 s = {0.f, 0.f, 0.f, 0.f};
    for (int i = 0; i < 16; ++i) {
        const float4 v = ((const float4*)part)[i * 4096 + j];
        s.x += v.x; s.y += v.y; s.z += v.z; s.w += v.w;
    }
    ((float4*)out)[j] = s;
}

extern "C" void kernel_launch(void* const* d_in, const int* in_sizes, int n_in,
                              void* d_out, int out_size, void* d_ws,
                              size_t ws_size, hipStream_t stream) {
    const float* hidden = (const float*)d_in[0];
    const float* enc    = (const float*)d_in[1];
    const float* Ww     = (const float*)d_in[2];
    const float* Wb     = (const float*)d_in[3];
    const float* Uw     = (const float*)d_in[4];
    const float* Ubias  = (const float*)d_in[5];
    const float* vw     = (const float*)d_in[6];

    float* out = (float*)d_out;  // [0,16384): context; [16384,...): weights

    char* ws = (char*)d_ws;
    float* bias          = (float*)(ws);                        // 64 KB
    unsigned short* Ub16 = (unsigned short*)(ws + (64 << 10));  // 512 KB
    float* scorep        = (float*)(ws + (576 << 10));          // 2x512 KB
    // part aliases [64K,1088K): Ub16 + scorep[0] dead after softmax
    float* part          = (float*)(ws + (64 << 10));           // 1 MB

    k_prep_bias<<<128, 256, 0, stream>>>(hidden, Ww, Wb, Ubias, bias);
    k_cvt<<<256, 256, 0, stream>>>(Uw, Ub16);
    k_gemm_score<<<(Mdim / BM) * 2, 512, 0, stream>>>(enc, Ub16, bias, vw,
                                                      scorep);
    k_softmax<<<Ndim, 256, 0, stream>>>(scorep, out + Ndim * Hdim);
    k_context<<<Ndim * (Sdim / 256), 512, 0, stream>>>(enc, out + Ndim * Hdim,
                                                       part);
    k_ctx_reduce<<<16, 256, 0, stream>>>(part, out);
}